// Round 13
// baseline (386.020 us; speedup 1.0000x reference)
//
#include <hip/hip_runtime.h>
#include <hip/hip_bf16.h>

// ============================================================================
// ConvTemporalGraphical — round 17: k34 without Bt LDS. Bt is pre-packed in
// MFMA-fragment order in GLOBAL memory (L2-resident), so each B-frag read is
// 1KB contiguous per wave. LDS drops 81,920 -> 52,224 B => 3 blocks/CU.
// k3 chains split 4-way (a0a/a0b/a1a/a1b) for 2x chain ILP.
//
//   k0: BtApck[nt][r][16c][4q][8j] u16 (r=0..8, BtA part; zero-padded).
//   k1: MFMA 80-ch 1x1 conv; hcn [n][t][64cc][32v] (r16).
//   k2a: MFMA Gram, 2-buffer parallel cross-wave reduce (r14).
//   k2b: 160 blocks; phase-3 now writes BtTp[n][nt][3i][16c][4q][8j].
//   k34: fused graph contraction + conv3d + BN + residual + relu.
//        No Bt stage: B-frags from BtApck/BtTp (L2). LDS = tile(19.2K)
//        overlaid by Csh(52.2K). launch_bounds(256,3).
//
// ws: a1o 0..13,158,400 | hcn ..80,267,264 | Spart 80,267,264..93,374,464 |
//     BtApck 130,598,912 | BtTp 130,644,992
// ============================================================================

typedef unsigned short u16;
typedef unsigned int   u32;
typedef __attribute__((ext_vector_type(8))) short bf16x8;
typedef __attribute__((ext_vector_type(4))) float f32x4;

__device__ __forceinline__ float b2f(u32 u) {
    union { u32 i; float f; } x; x.i = (u & 0xffffu) << 16; return x.f;
}
__device__ __forceinline__ u16 f2b(float f) {
    union { float f; u32 i; } x; x.f = f;
    u32 i = x.i;
    return (u16)((i + 0x7fffu + ((i >> 16) & 1u)) >> 16);   // RNE
}
__device__ __forceinline__ u32 pack2(float a, float b) {
    return (u32)f2b(a) | ((u32)f2b(b) << 16);
}

// ---------------------------------------------------------------------------
// k0: BtApck[((nt*9+r)*16+c)*4+q][8j] = Aeff^T fragment-ordered, zero-padded.
// ---------------------------------------------------------------------------
__global__ __launch_bounds__(256) void k0_bta(
    const float* __restrict__ A, const float* __restrict__ PA,
    u16* __restrict__ BtApck)
{
    int e = blockIdx.x * 256 + threadIdx.x;
    if (e >= 23040) return;
    const int nt  = e / 4608;
    const int rem = e - nt * 4608;
    const int r   = rem >> 9;              // 0..8
    const int c   = (rem >> 5) & 15;
    const int v   = rem & 31;              // q*8 + j
    const int w   = nt * 16 + c;
    const int g   = r / 3, i = r - g * 3;
    float val = 0.f;
    if (v < 25 && w < 75) {
        int idx = (g * 75 + i * 25 + v) * 75 + w;
        val = A[idx] + PA[idx];
    }
    BtApck[e] = f2b(val);
}

// ---------------------------------------------------------------------------
// k1: MFMA 80-ch 1x1 conv. Block = (n, 32 t's), 256 thr (4 waves), 4 stages.
// hcn stores: [n][t][cc][32v] — 4KB contiguous per t-panel.
// ---------------------------------------------------------------------------
__global__ __launch_bounds__(256, 2) void k1_conv80(
    const float* __restrict__ x,
    const float* __restrict__ wa, const float* __restrict__ ba,
    const float* __restrict__ wd, const float* __restrict__ bd,
    const float* __restrict__ wc, const float* __restrict__ bc,
    u16* __restrict__ a1o, u16* __restrict__ hcn)
{
    __shared__ __align__(16) u16 Xt[256 * 64];    // 32,768 B, [col][c] swizzled
    __shared__ __align__(16) u16 Csh[80 * 264];   // 42,240 B, [o][col] stride 264
    char* XtB = (char*)Xt;

    const int b    = blockIdx.x;
    const int n    = b >> 4;
    const int t0   = (b & 15) << 5;               // 32 t's per block
    const int tid  = threadIdx.x;
    const int wave = tid >> 6, lane = tid & 63;
    const int q    = lane >> 4, r = lane & 15;

    // --- per-block preload: W fragments (B-operand layout) + bias ---
    bf16x8 wfrag[5][2];
    float  breg[5];
    #pragma unroll
    for (int mt = 0; mt < 5; ++mt) {
        const int o = mt * 16 + r;
        const float* src = (o < 16) ? (wa + o * 64)
                         : (o < 32) ? (wd + (o - 16) * 64)
                                    : (wc + (o - 32) * 64);
        breg[mt] = (o < 16) ? ba[o] : (o < 32) ? bd[o - 16] : bc[o - 32];
        #pragma unroll
        for (int ks = 0; ks < 2; ++ks) {
            bf16x8 f;
            #pragma unroll
            for (int j = 0; j < 8; ++j)
                f[j] = (short)f2b(src[ks * 32 + q * 8 + j]);
            wfrag[mt][ks] = f;
        }
    }

    // --- a1o t-pad rows (ws is poisoned each launch) ---
    if (t0 == 0) {
        uint4 z; z.x = 0u; z.y = 0u; z.z = 0u; z.w = 0u;
        for (int e = tid; e < 50; e += 256)
            *(uint4*)&a1o[((size_t)n * 514) * 400 + e * 8] = z;
    }
    if (t0 == 480) {
        uint4 z; z.x = 0u; z.y = 0u; z.z = 0u; z.w = 0u;
        for (int e = tid; e < 50; e += 256)
            *(uint4*)&a1o[((size_t)n * 514 + 513) * 400 + e * 8] = z;
    }

    // --- zero Xt pad cols once (v = 25..31 per t; full 128B rows) ---
    {
        uint4 z; z.x = 0u; z.y = 0u; z.z = 0u; z.w = 0u;
        for (int e = tid; e < 448; e += 256) {
            const int pc = e >> 3, ch = e & 7;
            const int tl = pc / 7, pv = pc - tl * 7;
            const int col = tl * 32 + 25 + pv;
            *(uint4*)(XtB + col * 128 + ch * 16) = z;
        }
    }

    auto epilogue = [&](int tbp) {
        // hcn: [n][t][cc][32v]; e -> (tl, cc, v0): contiguous 4KB per tl.
        for (int e = tid; e < 2048; e += 256) {
            const int tl  = e >> 8;
            const int rem = e & 255;
            const int cc  = rem >> 2, v0 = (rem & 3) << 3;
            const int o   = (cc < 48) ? cc + 32 : cc - 32;
            uint4 pk = *(const uint4*)&Csh[o * 264 + tl * 32 + v0];
            *(uint4*)&hcn[(((size_t)n * 512 + (tbp + tl)) * 64 + cc) * 32 + v0] = pk;
        }
        for (int e = tid; e < 400; e += 256) {
            const int tv = e >> 1, h = (e & 1) << 3;
            const int tl = (tv * 41) >> 10;
            const int v  = tv - tl * 25;
            const int cb = tl * 32 + v;
            u16 a[8];
            #pragma unroll
            for (int k = 0; k < 8; ++k) a[k] = Csh[(h + k) * 264 + cb];
            uint4 pk;
            pk.x = (u32)a[0] | ((u32)a[1] << 16);
            pk.y = (u32)a[2] | ((u32)a[3] << 16);
            pk.z = (u32)a[4] | ((u32)a[5] << 16);
            pk.w = (u32)a[6] | ((u32)a[7] << 16);
            *(uint4*)&a1o[(((size_t)n * 514 + (tbp + tl + 1)) * 25 + v) * 16 + h] = pk;
        }
    };

    for (int s = 0; s < 4; ++s) {
        const int tb = t0 + s * 8;

        if (s > 0) epilogue(tb - 8);
        for (int e = tid; e < 400; e += 256) {
            const int co = e / 50;
            const int tq = e - co * 50;
            const float* gp = x + (((size_t)n * 64 + co * 8) * 512 + tb) * 25 + tq * 4;
            float fl[32];
            #pragma unroll
            for (int i = 0; i < 8; ++i) {
                const float4 t4 = *(const float4*)(gp + (size_t)i * 12800);
                fl[i * 4 + 0] = t4.x; fl[i * 4 + 1] = t4.y;
                fl[i * 4 + 2] = t4.z; fl[i * 4 + 3] = t4.w;
            }
            #pragma unroll
            for (int j = 0; j < 4; ++j) {
                const int tv  = tq * 4 + j;
                const int tl  = (tv * 41) >> 10;
                const int col = tl * 32 + (tv - tl * 25);
                uint4 pk;
                pk.x = pack2(fl[0 * 4 + j], fl[1 * 4 + j]);
                pk.y = pack2(fl[2 * 4 + j], fl[3 * 4 + j]);
                pk.z = pack2(fl[4 * 4 + j], fl[5 * 4 + j]);
                pk.w = pack2(fl[6 * 4 + j], fl[7 * 4 + j]);
                *(uint4*)(XtB + col * 128 + ((co * 16) ^ ((col & 7) << 4))) = pk;
            }
        }
        __syncthreads();

        {
            f32x4 acc[4][5];
            #pragma unroll
            for (int a_ = 0; a_ < 4; ++a_)
                #pragma unroll
                for (int m_ = 0; m_ < 5; ++m_)
                    acc[a_][m_] = (f32x4){0.f, 0.f, 0.f, 0.f};

            #pragma unroll
            for (int nt4 = 0; nt4 < 4; ++nt4) {
                const int col = (wave * 4 + nt4) * 16 + r;
                const int swz = (col & 7) << 4;
                const char* rowp = (const char*)Xt + col * 128;
                const bf16x8 x0 = *(const bf16x8*)(rowp + ((q * 16) ^ swz));
                const bf16x8 x1 = *(const bf16x8*)(rowp + ((64 + q * 16) ^ swz));
                #pragma unroll
                for (int mt = 0; mt < 5; ++mt) {
                    acc[nt4][mt] = __builtin_amdgcn_mfma_f32_16x16x32_bf16(
                        x0, wfrag[mt][0], acc[nt4][mt], 0, 0, 0);
                    acc[nt4][mt] = __builtin_amdgcn_mfma_f32_16x16x32_bf16(
                        x1, wfrag[mt][1], acc[nt4][mt], 0, 0, 0);
                }
            }
            #pragma unroll
            for (int nt4 = 0; nt4 < 4; ++nt4) {
                const int colb = (wave * 4 + nt4) * 16 + q * 4;
                #pragma unroll
                for (int mt = 0; mt < 5; ++mt) {
                    const int o = mt * 16 + r;
                    const float bi = breg[mt];
                    uint2 pr;
                    pr.x = pack2(acc[nt4][mt][0] + bi, acc[nt4][mt][1] + bi);
                    pr.y = pack2(acc[nt4][mt][2] + bi, acc[nt4][mt][3] + bi);
                    *(uint2*)&Csh[o * 264 + colb] = pr;
                }
            }
        }
        __syncthreads();
    }
    epilogue(t0 + 24);
}

// ---------------------------------------------------------------------------
// k2a: MFMA Gram matrix. Block = (n, 32-t chunk), 4 waves split k.
// 2-buffer parallel cross-wave reduce (r14).
// ---------------------------------------------------------------------------
__global__ __launch_bounds__(256, 2) void k2a_mfma(
    const u16* __restrict__ a1o, float* __restrict__ Spart)
{
    __shared__ u16 U[80 * 136];        // 21,760 B (stride 136: 2-way banks)
    __shared__ float Sred[80 * 80];    // 25,600 B
    __shared__ float Sred2[80 * 80];   // 25,600 B  (total 72,960 -> 2 blk/CU)
    const int b   = blockIdx.x;
    const int n   = b >> 4;
    const int tc  = b & 15;
    const int t0  = tc * 32;
    const int tid = threadIdx.x;
    const int wave = tid >> 6, lane = tid & 63;
    const int q = lane >> 4, col = lane & 15;

    f32x4 acc[25];
    #pragma unroll
    for (int i = 0; i < 25; ++i) acc[i] = (f32x4){0.f, 0.f, 0.f, 0.f};

    for (int s = 0; s < 4; ++s) {
        __syncthreads();                               // prior reads done
        for (int e = tid; e < 1280; e += 256) {        // stage 8 t's
            int row = e >> 4, c8 = (e & 15) << 3;
            uint4 val; val.x = 0u; val.y = 0u; val.z = 0u; val.w = 0u;
            if (row < 75) {
                int i = row / 25, v = row - i * 25;
                int tl = c8 >> 4, o0 = c8 & 8;
                int tp = t0 + s * 8 + tl + i;          // padded t idx, 0..513
                val = *(const uint4*)&a1o[(((size_t)n * 514 + tp) * 25 + v) * 16 + o0];
            }
            *(uint4*)&U[row * 136 + c8] = val;
        }
        __syncthreads();

        const int k0 = wave * 32 + q * 8;
        bf16x8 fr[5];
        #pragma unroll
        for (int r = 0; r < 5; ++r)
            fr[r] = *(const bf16x8*)&U[(r * 16 + col) * 136 + k0];
        #pragma unroll
        for (int mt = 0; mt < 5; ++mt)
            #pragma unroll
            for (int nt = 0; nt < 5; ++nt)
                acc[mt * 5 + nt] = __builtin_amdgcn_mfma_f32_16x16x32_bf16(
                    fr[mt], fr[nt], acc[mt * 5 + nt], 0, 0, 0);
    }

    // parallel reduce: waves 0/1 write Sred/Sred2; waves 2/3 add into them.
    if (wave < 2) {
        float* S = (wave == 0) ? Sred : Sred2;
        #pragma unroll
        for (int mt = 0; mt < 5; ++mt)
            #pragma unroll
            for (int nt = 0; nt < 5; ++nt)
                #pragma unroll
                for (int reg = 0; reg < 4; ++reg)
                    S[(mt * 16 + q * 4 + reg) * 80 + nt * 16 + col] =
                        acc[mt * 5 + nt][reg];
    }
    __syncthreads();
    if (wave >= 2) {
        float* S = (wave == 2) ? Sred : Sred2;
        #pragma unroll
        for (int mt = 0; mt < 5; ++mt)
            #pragma unroll
            for (int nt = 0; nt < 5; ++nt)
                #pragma unroll
                for (int reg = 0; reg < 4; ++reg)
                    S[(mt * 16 + q * 4 + reg) * 80 + nt * 16 + col] +=
                        acc[mt * 5 + nt][reg];
    }
    __syncthreads();
    float* dst = &Spart[(size_t)(n * 16 + tc) * 6400];
    for (int e = tid; e < 6400; e += 256) dst[e] = Sred[e] + Sred2[e];
}

// ---------------------------------------------------------------------------
// k2b: grid = (32 n x 5 w2-groups). Sum 16 partials, /75, column softmax;
// phase 3 writes BtTp[n][nt=w2g][3i][16c][4q][8j] (fragment order).
// ---------------------------------------------------------------------------
__global__ __launch_bounds__(256) void k2b_softmax(
    const float* __restrict__ Spart, u16* __restrict__ BtTp)
{
    __shared__ float S2[75][17];                  // [w1][w2l], pad to 17
    const int b = blockIdx.x;
    const int n = b / 5, w2g = b - n * 5;
    const int w2base = w2g * 16;
    const int tid = threadIdx.x;

    // phase 1: ks-reduction, 1200 elems
    for (int e = tid; e < 1200; e += 256) {
        const int w1 = e >> 4, w2l = e & 15;
        const float* sp = &Spart[(size_t)(n * 16) * 6400 + w1 * 80 + w2base + w2l];
        float s = 0.f;
        #pragma unroll
        for (int ks = 0; ks < 16; ++ks) s += sp[(size_t)ks * 6400];
        S2[w1][w2l] = s * (1.0f / 75.0f);
    }
    __syncthreads();

    // phase 2: softmax over w1, 16 lanes per column (cols are lane-contiguous)
    const int w2l = tid >> 4, j = tid & 15;
    float m = -1e30f;
    for (int w1 = j; w1 < 75; w1 += 16) m = fmaxf(m, S2[w1][w2l]);
    #pragma unroll
    for (int off = 8; off; off >>= 1) m = fmaxf(m, __shfl_xor(m, off, 16));
    float s = 0.f;
    for (int w1 = j; w1 < 75; w1 += 16) {
        const float e = __expf(S2[w1][w2l] - m);
        S2[w1][w2l] = e;
        s += e;
    }
    #pragma unroll
    for (int off = 8; off; off >>= 1) s += __shfl_xor(s, off, 16);
    const float r = 1.0f / s;
    for (int w1 = j; w1 < 75; w1 += 16) S2[w1][w2l] *= r;
    __syncthreads();

    // phase 3: fragment-ordered store (e = i*512 + c*32 + q*8 + j)
    for (int e = tid; e < 1536; e += 256) {
        const int i = e >> 9;
        const int c = (e >> 5) & 15;
        const int v = e & 31;
        const int w2 = w2base + c;
        const float val = (w2 < 75 && v < 25) ? S2[i * 25 + v][c] : 0.f;
        BtTp[((size_t)n * 5 + w2g) * 1536 + e] = f2b(val);
    }
}

// ---------------------------------------------------------------------------
// k34: fused graph contraction + conv3d + BN + residual + relu.
// Block = (n, 8 t's), 2048 blocks, LDS 52,224 B -> 3 blocks/CU.
// B-frags read directly from BtApck/BtTp (1KB coalesced, L2-resident).
// ---------------------------------------------------------------------------
__global__ __launch_bounds__(256, 3) void k34_fused(
    const u16* __restrict__ hcn, const u16* __restrict__ BtApck,
    const u16* __restrict__ BtTp,
    const float* __restrict__ ow, const float* __restrict__ obias,
    const float* __restrict__ bg, const float* __restrict__ bb,
    const float* __restrict__ bm, const float* __restrict__ bv,
    const float* __restrict__ x, float* __restrict__ out)
{
    __shared__ __align__(16) char smem[52224];
    u16*   tile = (u16*)smem;                    // [8 tl][1200] = 19,200 B
    float* Csh  = (float*)smem;                  // [64 o][204] overlay (tile dead)

    const int b    = blockIdx.x;
    const int n    = b >> 6;
    const int t0   = (b & 63) << 3;
    const int tid  = threadIdx.x;
    const int wave = tid >> 6, lane = tid & 63;
    const int q    = lane >> 4, c15 = lane & 15;

    // --- prefetch hcn frags (coalesced: 1KB per (g,t) per wave) ---
    const int tp = t0 + 2 * wave;
    bf16x8 frag[4][4];                 // frag[g][s] = hcn @ tp-1+s
    #pragma unroll
    for (int g = 0; g < 4; ++g)
        #pragma unroll
        for (int s2 = 0; s2 < 4; ++s2) {
            const int t = tp - 1 + s2;
            frag[g][s2] = (t >= 0 && t < 512)
                ? *(const bf16x8*)&hcn[(((size_t)n * 512 + t) * 64 + g * 16 + c15) * 32 + q * 8]
                : (bf16x8)(short)0;
        }

    // --- k3-part: wave computes t-pair (t0+2*wave, +1) -> LDS tile.
    //     B-frags from global (fragment-ordered, L2); 4 accumulation chains.
    const int lofs = (c15 * 4 + q) * 8;
    const u16* btTn = BtTp + (size_t)n * 5 * 1536;
    #pragma unroll 1
    for (int nt = 0; nt < 5; ++nt) {
        bf16x8 bfr[12];
        #pragma unroll
        for (int r = 0; r < 9; ++r)
            bfr[r] = *(const bf16x8*)&BtApck[(nt * 9 + r) * 512 + lofs];
        #pragma unroll
        for (int i = 0; i < 3; ++i)
            bfr[9 + i] = *(const bf16x8*)&btTn[nt * 1536 + i * 512 + lofs];

        f32x4 a0a = {0.f,0.f,0.f,0.f}, a0b = {0.f,0.f,0.f,0.f};
        f32x4 a1a = {0.f,0.f,0.f,0.f}, a1b = {0.f,0.f,0.f,0.f};
        #pragma unroll
        for (int g = 0; g < 4; ++g)
            #pragma unroll
            for (int i = 0; i < 3; ++i) {
                const int r = g * 3 + i;
                if (r < 6) {
                    a0a = __builtin_amdgcn_mfma_f32_16x16x32_bf16(bfr[r], frag[g][i],     a0a, 0, 0, 0);
                    a1a = __builtin_amdgcn_mfma_f32_16x16x32_bf16(bfr[r], frag[g][i + 1], a1a, 0, 0, 0);
                } else {
                    a0b = __builtin_amdgcn_mfma_f32_16x16x32_bf16(bfr[r], frag[g][i],     a0b, 0, 0, 0);
                    a1b = __builtin_amdgcn_mfma_f32_16x16x32_bf16(bfr[r], frag[g][i + 1], a1b, 0, 0, 0);
                }
            }
        const f32x4 acc0 = a0a + a0b;
        const f32x4 acc1 = a1a + a1b;
        #pragma unroll
        for (int reg = 0; reg < 4; ++reg) {
            const int w = nt * 16 + q * 4 + reg;
            if (w < 75) {
                const int ww = (w >= 50) ? 2 : ((w >= 25) ? 1 : 0);
                const int v  = w - ww * 25;
                const int off = (v * 3 + ww) * 16 + c15;
                tile[(2 * wave)     * 1200 + off] = f2b(acc0[reg]);
                tile[(2 * wave + 1) * 1200 + off] = f2b(acc1[reg]);
            }
        }
    }
    __syncthreads();                              // tile complete

    // --- k4-part: W2 fragments + MFMAs from tile ---
    bf16x8 wfrag[4][2];
    #pragma unroll
    for (int mt = 0; mt < 4; ++mt) {
        const int o = mt * 16 + c15;
        #pragma unroll
        for (int ks = 0; ks < 2; ++ks) {
            bf16x8 f;
            #pragma unroll
            for (int j = 0; j < 8; ++j) {
                const int k = ks * 32 + q * 8 + j;
                const int cc = k & 15, ww = k >> 4;
                f[j] = (k < 48) ? (short)f2b(ow[o * 48 + cc * 3 + ww]) : (short)0;
            }
            wfrag[mt][ks] = f;
        }
    }

    f32x4 acc[4][4];
    #pragma unroll
    for (int ct = 0; ct < 4; ++ct)
        #pragma unroll
        for (int mt = 0; mt < 4; ++mt)
            acc[ct][mt] = (f32x4){0.f, 0.f, 0.f, 0.f};

    const int wb = wave * 64;
    const int ww0 = q >> 1, cs2 = (q & 1) * 8;
    #pragma unroll
    for (int ct = 0; ct < 4; ++ct) {
        const int col = wb + ct * 16 + c15;
        const int tl = col >> 5, v = col & 31;
        const int vv = (v < 25) ? v : 0;          // clamp (garbage cols unused)
        const u16* trow = tile + tl * 1200;
        const bf16x8 b0 = *(const bf16x8*)&trow[(vv * 3 + ww0) * 16 + cs2];
        const bf16x8 b1 = *(const bf16x8*)&trow[(vv * 3 + 2) * 16 + cs2];
        #pragma unroll
        for (int mt = 0; mt < 4; ++mt) {
            acc[ct][mt] = __builtin_amdgcn_mfma_f32_16x16x32_bf16(
                wfrag[mt][0], b0, acc[ct][mt], 0, 0, 0);
            acc[ct][mt] = __builtin_amdgcn_mfma_f32_16x16x32_bf16(
                wfrag[mt][1], b1, acc[ct][mt], 0, 0, 0);
        }
    }
    __syncthreads();                              // tile reads done (Csh overlay)

    // --- BN consts + Csh writes ---
    float scl[4][4], shf2[4][4];
    #pragma unroll
    for (int mt = 0; mt < 4; ++mt)
        #pragma unroll
        for (int reg = 0; reg < 4; ++reg) {
            const int o = mt * 16 + q * 4 + reg;
            const float s = bg[o] * rsqrtf(bv[o] + 1e-5f);
            scl[mt][reg]  = s;
            shf2[mt][reg] = bb[o] + (obias[o] - bm[o]) * s;
        }
    #pragma unroll
    for (int ct = 0; ct < 4; ++ct) {
        const int col = wb + ct * 16 + c15;
        const int tl = col >> 5, v = col & 31;
        if (v < 25) {
            const int cc = tl * 25 + v;
            #pragma unroll
            for (int mt = 0; mt < 4; ++mt)
                #pragma unroll
                for (int reg = 0; reg < 4; ++reg) {
                    const int o = mt * 16 + q * 4 + reg;
                    Csh[o * 204 + cc] =
                        acc[ct][mt][reg] * scl[mt][reg] + shf2[mt][reg];
                }
        }
    }
    __syncthreads();

    // --- coalesced epilogue: float4 x-residual + relu + float4 out ---
    for (int e = tid; e < 3200; e += 256) {
        const int o = e / 50, jj = e - o * 50;
        const size_t gidx = (((size_t)n * 64 + o) * 512 + t0) * 25 + jj * 4;
        const float4 xv = *(const float4*)&x[gidx];
        const float* cp = &Csh[o * 204 + jj * 4];
        float4 yv;
        yv.x = fmaxf(cp[0] + xv.x, 0.f);
        yv.y = fmaxf(cp[1] + xv.y, 0.f);
        yv.z = fmaxf(cp[2] + xv.z, 0.f);
        yv.w = fmaxf(cp[3] + xv.w, 0.f);
        *(float4*)&out[gidx] = yv;
    }
}

// ---------------------------------------------------------------------------
extern "C" void kernel_launch(void* const* d_in, const int* in_sizes, int n_in,
                              void* d_out, int out_size, void* d_ws, size_t ws_size,
                              hipStream_t stream)
{
    const float* x  = (const float*)d_in[0];
    const float* A  = (const float*)d_in[1];
    const float* PA = (const float*)d_in[2];
    const float* wa = (const float*)d_in[3];
    const float* ba = (const float*)d_in[4];
    const float* wd = (const float*)d_in[5];
    const float* bd = (const float*)d_in[6];
    const float* wc = (const float*)d_in[7];
    const float* bc = (const float*)d_in[8];
    const float* ow = (const float*)d_in[9];
    const float* ob = (const float*)d_in[10];
    const float* bg = (const float*)d_in[11];
    const float* bb = (const float*)d_in[12];
    const float* bm = (const float*)d_in[13];
    const float* bv = (const float*)d_in[14];
    float* out = (float*)d_out;

    char* ws = (char*)d_ws;
    u16*   a1o    = (u16*)(ws);                          // 13,158,400 B
    u16*   hcn    = (u16*)(ws + 13158400);               // 67,108,864 B
    float* Spart  = (float*)(ws + 80267264);             // 13,107,200 B
    u16*   BtApck = (u16*)(ws + 130598912);              // 46,080 B
    u16*   BtTp   = (u16*)(ws + 130644992);              // 491,520 B
    // total 131,136,512 B

    k0_bta    <<<90,   256, 0, stream>>>(A, PA, BtApck);
    k1_conv80 <<<512,  256, 0, stream>>>(x, wa, ba, wd, bd, wc, bc, a1o, hcn);
    k2a_mfma  <<<512,  256, 0, stream>>>(a1o, Spart);
    k2b_softmax<<<160, 256, 0, stream>>>(Spart, BtTp);
    k34_fused <<<2048, 256, 0, stream>>>(hcn, BtApck, BtTp, ow, ob, bg, bb, bm, bv, x, out);
}